// Round 7
// baseline (230.045 us; speedup 1.0000x reference)
//
#include <hip/hip_runtime.h>
#include <math.h>

typedef __bf16 bf16;
typedef __bf16 bf16x4 __attribute__((ext_vector_type(4)));
typedef __bf16 bf16x8 __attribute__((ext_vector_type(8)));
typedef float f32x4 __attribute__((ext_vector_type(4)));
typedef float f32x16 __attribute__((ext_vector_type(16)));

typedef void __attribute__((address_space(1))) as1_void;
typedef void __attribute__((address_space(3))) as3_void;

// async global->LDS, 16B per lane. LDS dest = wave-uniform base + lane*16.
__device__ __forceinline__ void async16(const void* g, void* l) {
  __builtin_amdgcn_global_load_lds((as1_void*)(void*)g, (as3_void*)l, 16, 0, 0);
}

// ---------------- fused cast fp32 -> bf16 for all 7 tensors ----------------
__global__ void cast_all(const float* __restrict__ s0, const float* __restrict__ s1,
                         const float* __restrict__ s2, const float* __restrict__ s3,
                         const float* __restrict__ s4, const float* __restrict__ s5,
                         const float* __restrict__ s6, bf16* __restrict__ dst) {
  int i = blockIdx.x * 256 + threadIdx.x;  // float4 index, uniform segment per block
  const float* src; int base;
  if (i < 3145728) { int t = i >> 20; src = (t == 0) ? s0 : (t == 1 ? s1 : s2); base = t << 20; }
  else {
    int t = (i - 3145728) >> 18;
    src = (t == 0) ? s3 : (t == 1 ? s4 : (t == 2 ? s5 : s6));
    base = 3145728 + (t << 18);
  }
  float4 f = ((const float4*)src)[i - base];
  bf16x4 o; o[0] = (bf16)f.x; o[1] = (bf16)f.y; o[2] = (bf16)f.z; o[3] = (bf16)f.w;
  *(bf16x4*)(dst + (size_t)i * 4) = o;
}

// ---------------- GEMM core: 128x128 tile, K=1024, C = A @ W^T ----------------
template<int SWAP>
__device__ __forceinline__ void gemm_core(const bf16* __restrict__ A, const bf16* __restrict__ W,
                                          bf16* sA, bf16* sB, int m0, int n0, f32x4 acc[4][4]) {
  const int tid = threadIdx.x;
  const int wave = tid >> 6, lane = tid & 63, quad = lane >> 4, l16 = lane & 15;
  const int wm = (wave >> 1) * 64, wn = (wave & 1) * 64;
  for (int kt = 0; kt < 1024; kt += 64) {
    #pragma unroll
    for (int i = 0; i < 4; ++i) {
      int c = i * 256 + tid;
      int row = c >> 3, cg = c & 7;
      int gc = kt + ((cg ^ (row & 7)) << 3);
      async16(A + (size_t)(m0 + row) * 1024 + gc, (char*)sA + i * 4096 + wave * 1024);
      async16(W + (size_t)(n0 + row) * 1024 + gc, (char*)sB + i * 4096 + wave * 1024);
    }
    __syncthreads();
    #pragma unroll
    for (int kk = 0; kk < 2; ++kk) {
      bf16x8 af[4], bw[4];
      #pragma unroll
      for (int mi = 0; mi < 4; mi++) {
        int row = wm + mi * 16 + l16;
        af[mi] = *(const bf16x8*)&sA[row * 64 + (((quad + kk * 4) ^ (row & 7)) << 3)];
      }
      #pragma unroll
      for (int ni = 0; ni < 4; ni++) {
        int row = wn + ni * 16 + l16;
        bw[ni] = *(const bf16x8*)&sB[row * 64 + (((quad + kk * 4) ^ (row & 7)) << 3)];
      }
      #pragma unroll
      for (int mi = 0; mi < 4; mi++)
        #pragma unroll
        for (int ni = 0; ni < 4; ni++)
          acc[mi][ni] = SWAP
            ? __builtin_amdgcn_mfma_f32_16x16x32_bf16(bw[ni], af[mi], acc[mi][ni], 0, 0, 0)
            : __builtin_amdgcn_mfma_f32_16x16x32_bf16(af[mi], bw[ni], acc[mi][ni], 0, 0, 0);
    }
    __syncthreads();
  }
}

// ---------------- fused QKV projection: grid.z selects q/k/v ----------------
// z=0,1: out[m][n] bf16 (SWAP path). z=0 (Q) pre-scaled by 0.125.
// z=2:   Vt[b][h][d][s-pi] bf16 with key-permutation pi16 (swap s%16: 4..7 <-> 8..11)
//        baked in so attention's PV can consume P straight from MFMA C registers.
__global__ __launch_bounds__(256, 3)
void gemm_qkv(const bf16* __restrict__ A0, const bf16* __restrict__ A1, const bf16* __restrict__ A2,
              const bf16* __restrict__ W0, const bf16* __restrict__ W1, const bf16* __restrict__ W2,
              const float* __restrict__ b0, const float* __restrict__ b1, const float* __restrict__ b2,
              bf16* __restrict__ Qp, bf16* __restrict__ Kp, bf16* __restrict__ Vt) {
  __shared__ __align__(16) bf16 sA[128 * 64];
  __shared__ __align__(16) bf16 sB[128 * 64];
  const int z = blockIdx.z;
  const bf16* A = (z == 0) ? A0 : (z == 1 ? A1 : A2);
  const bf16* W = (z == 0) ? W0 : (z == 1 ? W1 : W2);
  const float* bias = (z == 0) ? b0 : (z == 1 ? b1 : b2);
  const int m0 = blockIdx.y * 128, n0 = blockIdx.x * 128;
  const int tid = threadIdx.x;
  const int wave = tid >> 6, lane = tid & 63, quad = lane >> 4, l16 = lane & 15;
  const int wm = (wave >> 1) * 64, wn = (wave & 1) * 64;

  f32x4 acc[4][4];
  #pragma unroll
  for (int mi = 0; mi < 4; mi++)
    #pragma unroll
    for (int ni = 0; ni < 4; ni++)
      #pragma unroll
      for (int r = 0; r < 4; r++) acc[mi][ni][r] = 0.f;

  if (z < 2) {
    gemm_core<1>(A, W, sA, sB, m0, n0, acc);
    bf16* out = (z == 0) ? Qp : Kp;
    const float sc = (z == 0) ? 0.125f : 1.0f;  // fold 1/sqrt(64) into Q (exact pow2)
    #pragma unroll
    for (int mi = 0; mi < 4; mi++) {
      int m = m0 + wm + mi * 16 + l16;
      #pragma unroll
      for (int ni = 0; ni < 4; ni++) {
        int nb = n0 + wn + ni * 16 + quad * 4;
        f32x4 b4 = *(const f32x4*)&bias[nb];
        bf16x4 o;
        #pragma unroll
        for (int r = 0; r < 4; r++) o[r] = (bf16)((acc[mi][ni][r] + b4[r]) * sc);
        *(bf16x4*)&out[(size_t)m * 1024 + nb] = o;
      }
    }
  } else {
    gemm_core<0>(A, W, sA, sB, m0, n0, acc);
    #pragma unroll
    for (int ni = 0; ni < 4; ni++) {
      int n_g = n0 + wn + ni * 16 + l16;  // column of E = (h,d)
      float bs = bias[n_g];
      int h = n_g >> 6, d = n_g & 63;
      #pragma unroll
      for (int mi = 0; mi < 4; mi++) {
        int m_b = m0 + wm + mi * 16 + quad * 4;  // 4 consecutive s, s%16 in {0,4,8,12}
        int b = m_b >> 11, s0 = m_b & 2047;
        int sp = s0 & 15;
        int spp = (sp == 4) ? 8 : ((sp == 8) ? 4 : sp);   // pi16 involution
        int s1 = (s0 & ~15) | spp;
        bf16x4 o;
        #pragma unroll
        for (int r = 0; r < 4; r++) o[r] = (bf16)(acc[mi][ni][r] + bs);
        *(bf16x4*)&Vt[(size_t)((b * 16 + h) * 64 + d) * 2048 + s1] = o;
      }
    }
  }
}

// ---------------- output projection: 128x64 tile, + bias + residual ----------------
__global__ __launch_bounds__(256, 2)
void gemm_o(const bf16* __restrict__ A, const bf16* __restrict__ W,
            const float* __restrict__ bias, const float* __restrict__ resid,
            float* __restrict__ out) {
  __shared__ __align__(16) bf16 sA[128 * 64];
  __shared__ __align__(16) bf16 sB[64 * 64];
  const int m0 = blockIdx.y * 128, n0 = blockIdx.x * 64;
  const int tid = threadIdx.x;
  const int wave = tid >> 6, lane = tid & 63, quad = lane >> 4, l16 = lane & 15;
  const int wm = (wave >> 1) * 64, wn = (wave & 1) * 32;

  f32x4 acc[4][2];
  #pragma unroll
  for (int mi = 0; mi < 4; mi++)
    #pragma unroll
    for (int ni = 0; ni < 2; ni++)
      #pragma unroll
      for (int r = 0; r < 4; r++) acc[mi][ni][r] = 0.f;

  for (int kt = 0; kt < 1024; kt += 64) {
    #pragma unroll
    for (int i = 0; i < 4; ++i) {
      int c = i * 256 + tid;
      int row = c >> 3, cg = c & 7;
      async16(A + (size_t)(m0 + row) * 1024 + kt + ((cg ^ (row & 7)) << 3),
              (char*)sA + i * 4096 + wave * 1024);
    }
    #pragma unroll
    for (int i = 0; i < 2; ++i) {
      int c = i * 256 + tid;
      int row = c >> 3, cg = c & 7;
      async16(W + (size_t)(n0 + row) * 1024 + kt + ((cg ^ (row & 7)) << 3),
              (char*)sB + i * 4096 + wave * 1024);
    }
    __syncthreads();
    #pragma unroll
    for (int kk = 0; kk < 2; ++kk) {
      bf16x8 af[4], bw[2];
      #pragma unroll
      for (int mi = 0; mi < 4; mi++) {
        int row = wm + mi * 16 + l16;
        af[mi] = *(const bf16x8*)&sA[row * 64 + (((quad + kk * 4) ^ (row & 7)) << 3)];
      }
      #pragma unroll
      for (int ni = 0; ni < 2; ni++) {
        int row = wn + ni * 16 + l16;
        bw[ni] = *(const bf16x8*)&sB[row * 64 + (((quad + kk * 4) ^ (row & 7)) << 3)];
      }
      #pragma unroll
      for (int mi = 0; mi < 4; mi++)
        #pragma unroll
        for (int ni = 0; ni < 2; ni++)
          acc[mi][ni] = __builtin_amdgcn_mfma_f32_16x16x32_bf16(bw[ni], af[mi], acc[mi][ni], 0, 0, 0);
    }
    __syncthreads();
  }
  #pragma unroll
  for (int mi = 0; mi < 4; mi++) {
    int m = m0 + wm + mi * 16 + l16;
    #pragma unroll
    for (int ni = 0; ni < 2; ni++) {
      int nb = n0 + wn + ni * 16 + quad * 4;
      f32x4 b4 = *(const f32x4*)&bias[nb];
      f32x4 r4 = *(const f32x4*)&resid[(size_t)m * 1024 + nb];
      f32x4 o;
      #pragma unroll
      for (int r = 0; r < 4; r++) o[r] = acc[mi][ni][r] + b4[r] + r4[r];
      *(f32x4*)&out[(size_t)m * 1024 + nb] = o;
    }
  }
}

// ---------------- flash attention: 32x32x16 MFMA, register-resident P ----------------
// Qp (pre-scaled), Kp: [B,S,E] bf16. Vt: [B,H,64,2048] bf16 with pi16-permuted keys.
// Block: 256 q (4 waves x 2 qg x 32), K-tiles of 128, double-buffered sK/sV (64KB).
// S^T = mfma32(K,Q): C[key][q=lane&31], 16 keys/lane. exp2 -> pack pairs -> bf16x8
// IS the PV B-operand for pi-permuted keys (C regs 8s+j == B-frag elem j, kstep s).
// PV: O^T = mfma32(V', P): C[d][q] -> per-lane l (defer reduce), 8B stores.
__global__ __launch_bounds__(256, 1)
void attn_fused(const bf16* __restrict__ Qp, const bf16* __restrict__ Kp,
                const bf16* __restrict__ Vt, const unsigned char* __restrict__ mask,
                bf16* __restrict__ AO)
{
  __shared__ __align__(16) bf16 sK[2 * 128 * 64];   // 32KB dbuf [key][d] swizzled
  __shared__ __align__(16) bf16 sV[2 * 64 * 128];   // 32KB dbuf [d][key-pi] swizzled
  const int tid = threadIdx.x;
  const int wave = tid >> 6, lane = tid & 63, l31 = lane & 31, hl = lane >> 5;
  const int bh = blockIdx.x, qt = blockIdx.y;
  const int b = bh >> 4, h = bh & 15;
  const int q0 = qt * 256;
  const bf16* Kbase = Kp + (size_t)(b * 2048) * 1024 + h * 64;
  const bf16* Vbase = Vt + (size_t)bh * 64 * 2048;

  // Q B-frags from global: lane(q=l31,hl) holds Q[q][ks*16 + hl*8 .. +7]
  bf16x8 qf[2][4];
  #pragma unroll
  for (int qg = 0; qg < 2; qg++) {
    const bf16* Qrow = Qp + (size_t)(b * 2048 + q0 + wave * 64 + qg * 32 + l31) * 1024 + h * 64;
    #pragma unroll
    for (int ks = 0; ks < 4; ks++)
      qf[qg][ks] = *(const bf16x8*)(Qrow + ks * 16 + hl * 8);
  }

  // hoisted mask any-check (whole row, once): 2048 bytes / 64 lanes = 8 u32 each
  unsigned mor = 0;
  #pragma unroll
  for (int i = 0; i < 8; i++)
    mor |= ((const unsigned*)(mask + b * 2048))[lane + i * 64];
  const bool anymask = __any(mor != 0);

  auto stageKV = [&](int kt, int buf) {
    int k0 = kt * 128;
    char* dK = (char*)sK + buf * 16384;
    char* dV = (char*)sV + buf * 16384;
    #pragma unroll
    for (int i = 0; i < 4; i++) {
      int c = i * 256 + tid;
      int rk = c >> 3, cgk = c & 7;
      async16(Kbase + (size_t)(k0 + rk) * 1024 + ((cgk ^ (rk & 7)) << 3),
              dK + i * 4096 + wave * 1024);
      int d = c >> 4, cgv = c & 15;
      async16(Vbase + (size_t)d * 2048 + k0 + ((cgv ^ (d & 15)) << 3),
              dV + i * 4096 + wave * 1024);
    }
  };

  float l_lane[2] = {0.f, 0.f};
  f32x16 oacc[2][2];  // [qg][d-block]
  #pragma unroll
  for (int qg = 0; qg < 2; qg++)
    #pragma unroll
    for (int db = 0; db < 2; db++)
      #pragma unroll
      for (int r = 0; r < 16; r++) oacc[qg][db][r] = 0.f;

  stageKV(0, 0);
  const float L2E = 1.44269504f;

  for (int kt = 0; kt < 16; ++kt) {
    int buf = kt & 1;
    __syncthreads();                       // staging(cur) drained; prev reads done
    if (kt < 15) stageKV(kt + 1, buf ^ 1); // overlaps with compute below
    const bf16* kbuf = sK + buf * 8192;
    const bf16* vbuf = sV + buf * 8192;

    // S^T: sacc[qg][kb]: C[key = kb*32 + (reg&3)+8*(reg>>2)+4*hl][q = l31]
    f32x16 sacc[2][4];
    #pragma unroll
    for (int qg = 0; qg < 2; qg++)
      #pragma unroll
      for (int kb = 0; kb < 4; kb++)
        #pragma unroll
        for (int r = 0; r < 16; r++) sacc[qg][kb][r] = 0.f;
    #pragma unroll
    for (int ks = 0; ks < 4; ks++)
      #pragma unroll
      for (int kb = 0; kb < 4; kb++) {
        bf16x8 ak = *(const bf16x8*)&kbuf[(kb * 32 + l31) * 64 + (((2 * ks + hl) ^ (l31 & 7)) << 3)];
        sacc[0][kb] = __builtin_amdgcn_mfma_f32_32x32x16_bf16(ak, qf[0][ks], sacc[0][kb], 0, 0, 0);
        sacc[1][kb] = __builtin_amdgcn_mfma_f32_32x32x16_bf16(ak, qf[1][ks], sacc[1][kb], 0, 0, 0);
      }

    if (anymask) {  // rare path: masked keys -> -1e30 -> exp2 -> 0
      int mbase = b * 2048 + kt * 128;
      #pragma unroll
      for (int kb = 0; kb < 4; kb++)
        #pragma unroll
        for (int g2 = 0; g2 < 4; g2++) {
          unsigned m4 = *(const unsigned*)&mask[mbase + kb * 32 + g2 * 8 + hl * 4];
          #pragma unroll
          for (int rr = 0; rr < 4; rr++)
            if ((m4 >> (8 * rr)) & 0xff) {
              sacc[0][kb][g2 * 4 + rr] = -1e30f;
              sacc[1][kb][g2 * 4 + rr] = -1e30f;
            }
        }
    }

    // exp2 + pack: pfrag[qg][kb][s][j] = exp2(sacc regs 8s+j) -- directly the PV B-frag
    bf16x8 pfrag[2][4][2];
    #pragma unroll
    for (int qg = 0; qg < 2; qg++) {
      float rs = 0.f;
      #pragma unroll
      for (int kb = 0; kb < 4; kb++)
        #pragma unroll
        for (int s = 0; s < 2; s++)
          #pragma unroll
          for (int j = 0; j < 8; j++) {
            float p = __builtin_amdgcn_exp2f(sacc[qg][kb][8 * s + j] * L2E);
            rs += p;
            pfrag[qg][kb][s][j] = (bf16)p;
          }
      l_lane[qg] += rs;
    }

    // O^T += V' . P  (V-frags shared across qg)
    #pragma unroll
    for (int kb = 0; kb < 4; kb++)
      #pragma unroll
      for (int s = 0; s < 2; s++) {
        int g = kb * 2 + s;
        #pragma unroll
        for (int db = 0; db < 2; db++) {
          bf16x8 av = *(const bf16x8*)&vbuf[(db * 32 + l31) * 128 + (((2 * g + hl) ^ (l31 & 15)) << 3)];
          oacc[0][db] = __builtin_amdgcn_mfma_f32_32x32x16_bf16(av, pfrag[0][kb][s], oacc[0][db], 0, 0, 0);
          oacc[1][db] = __builtin_amdgcn_mfma_f32_32x32x16_bf16(av, pfrag[1][kb][s], oacc[1][db], 0, 0, 0);
        }
      }
  }

  // finalize: l = lane + xor32 partner (key halves); O^T rows d -> 8B stores
  #pragma unroll
  for (int qg = 0; qg < 2; qg++) {
    float l = l_lane[qg] + __shfl_xor(l_lane[qg], 32);
    float inv = 1.0f / l;
    int s = q0 + wave * 64 + qg * 32 + l31;
    #pragma unroll
    for (int db = 0; db < 2; db++)
      #pragma unroll
      for (int g2 = 0; g2 < 4; g2++) {
        bf16x4 o;
        #pragma unroll
        for (int r = 0; r < 4; r++) o[r] = (bf16)(oacc[qg][db][g2 * 4 + r] * inv);
        *(bf16x4*)&AO[(size_t)(b * 2048 + s) * 1024 + h * 64 + db * 32 + g2 * 8 + hl * 4] = o;
      }
  }
}

extern "C" void kernel_launch(void* const* d_in, const int* in_sizes, int n_in,
                              void* d_out, int out_size, void* d_ws, size_t ws_size,
                              hipStream_t stream) {
  (void)in_sizes; (void)n_in; (void)out_size; (void)ws_size;
  const float* qf = (const float*)d_in[0];
  const float* kf = (const float*)d_in[1];
  const float* vf = (const float*)d_in[2];
  const unsigned char* mask = (const unsigned char*)d_in[3];
  const float* Wq = (const float*)d_in[4];
  const float* bq = (const float*)d_in[5];
  const float* Wk = (const float*)d_in[6];
  const float* bk = (const float*)d_in[7];
  const float* Wv = (const float*)d_in[8];
  const float* bv = (const float*)d_in[9];
  const float* Wo = (const float*)d_in[10];
  const float* bo = (const float*)d_in[11];

  bf16* p = (bf16*)d_ws;  // cast block must stay contiguous: Qb|Kb|Vb|Wqb|Wkb|Wvb|Wob
  bf16* Qb  = p; p += 4194304;
  bf16* Kb  = p; p += 4194304;
  bf16* Vb  = p; p += 4194304;
  bf16* Wqb = p; p += 1048576;
  bf16* Wkb = p; p += 1048576;
  bf16* Wvb = p; p += 1048576;
  bf16* Wob = p; p += 1048576;
  bf16* Qp  = p; p += 4194304;
  bf16* Kp  = p; p += 4194304;
  bf16* Vtp = p; p += 4194304;
  bf16* AO  = p; p += 4194304;

  cast_all<<<16384, 256, 0, stream>>>(qf, kf, vf, Wq, Wk, Wv, Wo, Qb);
  gemm_qkv<<<dim3(8, 32, 3), 256, 0, stream>>>(Qb, Kb, Vb, Wqb, Wkb, Wvb,
                                               bq, bk, bv, Qp, Kp, Vtp);
  attn_fused<<<dim3(32, 8), 256, 0, stream>>>(Qp, Kp, Vtp, mask, AO);
  gemm_o<<<dim3(16, 32), 256, 0, stream>>>(AO, Wob, bo, qf, (float*)d_out);
}

// Round 8
// 222.807 us; speedup vs baseline: 1.0325x; 1.0325x over previous
//
#include <hip/hip_runtime.h>
#include <math.h>

typedef __bf16 bf16;
typedef __bf16 bf16x4 __attribute__((ext_vector_type(4)));
typedef __bf16 bf16x8 __attribute__((ext_vector_type(8)));
typedef float f32x4 __attribute__((ext_vector_type(4)));
typedef float f32x16 __attribute__((ext_vector_type(16)));

typedef void __attribute__((address_space(1))) as1_void;
typedef void __attribute__((address_space(3))) as3_void;

// async global->LDS, 16B per lane. LDS dest = wave-uniform base + lane*16.
__device__ __forceinline__ void async16(const void* g, void* l) {
  __builtin_amdgcn_global_load_lds((as1_void*)(void*)g, (as3_void*)l, 16, 0, 0);
}

// ---------------- fused cast fp32 -> bf16 for all 7 tensors ----------------
__global__ void cast_all(const float* __restrict__ s0, const float* __restrict__ s1,
                         const float* __restrict__ s2, const float* __restrict__ s3,
                         const float* __restrict__ s4, const float* __restrict__ s5,
                         const float* __restrict__ s6, bf16* __restrict__ dst) {
  int i = blockIdx.x * 256 + threadIdx.x;  // float4 index, uniform segment per block
  const float* src; int base;
  if (i < 3145728) { int t = i >> 20; src = (t == 0) ? s0 : (t == 1 ? s1 : s2); base = t << 20; }
  else {
    int t = (i - 3145728) >> 18;
    src = (t == 0) ? s3 : (t == 1 ? s4 : (t == 2 ? s5 : s6));
    base = 3145728 + (t << 18);
  }
  float4 f = ((const float4*)src)[i - base];
  bf16x4 o; o[0] = (bf16)f.x; o[1] = (bf16)f.y; o[2] = (bf16)f.z; o[3] = (bf16)f.w;
  *(bf16x4*)(dst + (size_t)i * 4) = o;
}

// ---------------- GEMM core: 128x128 tile, K=1024, C = A @ W^T ----------------
template<int SWAP>
__device__ __forceinline__ void gemm_core(const bf16* __restrict__ A, const bf16* __restrict__ W,
                                          bf16* sA, bf16* sB, int m0, int n0, f32x4 acc[4][4]) {
  const int tid = threadIdx.x;
  const int wave = tid >> 6, lane = tid & 63, quad = lane >> 4, l16 = lane & 15;
  const int wm = (wave >> 1) * 64, wn = (wave & 1) * 64;
  for (int kt = 0; kt < 1024; kt += 64) {
    #pragma unroll
    for (int i = 0; i < 4; ++i) {
      int c = i * 256 + tid;
      int row = c >> 3, cg = c & 7;
      int gc = kt + ((cg ^ (row & 7)) << 3);
      async16(A + (size_t)(m0 + row) * 1024 + gc, (char*)sA + i * 4096 + wave * 1024);
      async16(W + (size_t)(n0 + row) * 1024 + gc, (char*)sB + i * 4096 + wave * 1024);
    }
    __syncthreads();
    #pragma unroll
    for (int kk = 0; kk < 2; ++kk) {
      bf16x8 af[4], bw[4];
      #pragma unroll
      for (int mi = 0; mi < 4; mi++) {
        int row = wm + mi * 16 + l16;
        af[mi] = *(const bf16x8*)&sA[row * 64 + (((quad + kk * 4) ^ (row & 7)) << 3)];
      }
      #pragma unroll
      for (int ni = 0; ni < 4; ni++) {
        int row = wn + ni * 16 + l16;
        bw[ni] = *(const bf16x8*)&sB[row * 64 + (((quad + kk * 4) ^ (row & 7)) << 3)];
      }
      #pragma unroll
      for (int mi = 0; mi < 4; mi++)
        #pragma unroll
        for (int ni = 0; ni < 4; ni++)
          acc[mi][ni] = SWAP
            ? __builtin_amdgcn_mfma_f32_16x16x32_bf16(bw[ni], af[mi], acc[mi][ni], 0, 0, 0)
            : __builtin_amdgcn_mfma_f32_16x16x32_bf16(af[mi], bw[ni], acc[mi][ni], 0, 0, 0);
    }
    __syncthreads();
  }
}

// ---------------- fused QKV projection: grid.z selects q/k/v ----------------
// z=0,1: out[m][n] bf16 (SWAP path). z=0 (Q) pre-scaled by 0.125.
// z=2:   Vt[b][h][d][s-pi] bf16 with key-permutation pi16 (swap s%16: 4..7 <-> 8..11)
//        baked in so attention's PV can consume P straight from MFMA C registers.
__global__ __launch_bounds__(256, 3)
void gemm_qkv(const bf16* __restrict__ A0, const bf16* __restrict__ A1, const bf16* __restrict__ A2,
              const bf16* __restrict__ W0, const bf16* __restrict__ W1, const bf16* __restrict__ W2,
              const float* __restrict__ b0, const float* __restrict__ b1, const float* __restrict__ b2,
              bf16* __restrict__ Qp, bf16* __restrict__ Kp, bf16* __restrict__ Vt) {
  __shared__ __align__(16) bf16 sA[128 * 64];
  __shared__ __align__(16) bf16 sB[128 * 64];
  const int z = blockIdx.z;
  const bf16* A = (z == 0) ? A0 : (z == 1 ? A1 : A2);
  const bf16* W = (z == 0) ? W0 : (z == 1 ? W1 : W2);
  const float* bias = (z == 0) ? b0 : (z == 1 ? b1 : b2);
  const int m0 = blockIdx.y * 128, n0 = blockIdx.x * 128;
  const int tid = threadIdx.x;
  const int wave = tid >> 6, lane = tid & 63, quad = lane >> 4, l16 = lane & 15;
  const int wm = (wave >> 1) * 64, wn = (wave & 1) * 64;

  f32x4 acc[4][4];
  #pragma unroll
  for (int mi = 0; mi < 4; mi++)
    #pragma unroll
    for (int ni = 0; ni < 4; ni++)
      #pragma unroll
      for (int r = 0; r < 4; r++) acc[mi][ni][r] = 0.f;

  if (z < 2) {
    gemm_core<1>(A, W, sA, sB, m0, n0, acc);
    bf16* out = (z == 0) ? Qp : Kp;
    const float sc = (z == 0) ? 0.125f : 1.0f;  // fold 1/sqrt(64) into Q (exact pow2)
    #pragma unroll
    for (int mi = 0; mi < 4; mi++) {
      int m = m0 + wm + mi * 16 + l16;
      #pragma unroll
      for (int ni = 0; ni < 4; ni++) {
        int nb = n0 + wn + ni * 16 + quad * 4;
        f32x4 b4 = *(const f32x4*)&bias[nb];
        bf16x4 o;
        #pragma unroll
        for (int r = 0; r < 4; r++) o[r] = (bf16)((acc[mi][ni][r] + b4[r]) * sc);
        *(bf16x4*)&out[(size_t)m * 1024 + nb] = o;
      }
    }
  } else {
    gemm_core<0>(A, W, sA, sB, m0, n0, acc);
    #pragma unroll
    for (int ni = 0; ni < 4; ni++) {
      int n_g = n0 + wn + ni * 16 + l16;  // column of E = (h,d)
      float bs = bias[n_g];
      int h = n_g >> 6, d = n_g & 63;
      #pragma unroll
      for (int mi = 0; mi < 4; mi++) {
        int m_b = m0 + wm + mi * 16 + quad * 4;  // 4 consecutive s, s%16 in {0,4,8,12}
        int b = m_b >> 11, s0 = m_b & 2047;
        int sp = s0 & 15;
        int spp = (sp == 4) ? 8 : ((sp == 8) ? 4 : sp);   // pi16 involution
        int s1 = (s0 & ~15) | spp;
        bf16x4 o;
        #pragma unroll
        for (int r = 0; r < 4; r++) o[r] = (bf16)(acc[mi][ni][r] + bs);
        *(bf16x4*)&Vt[(size_t)((b * 16 + h) * 64 + d) * 2048 + s1] = o;
      }
    }
  }
}

// ---------------- output projection: 128x64 tile, + bias + residual ----------------
__global__ __launch_bounds__(256, 2)
void gemm_o(const bf16* __restrict__ A, const bf16* __restrict__ W,
            const float* __restrict__ bias, const float* __restrict__ resid,
            float* __restrict__ out) {
  __shared__ __align__(16) bf16 sA[128 * 64];
  __shared__ __align__(16) bf16 sB[64 * 64];
  const int m0 = blockIdx.y * 128, n0 = blockIdx.x * 64;
  const int tid = threadIdx.x;
  const int wave = tid >> 6, lane = tid & 63, quad = lane >> 4, l16 = lane & 15;
  const int wm = (wave >> 1) * 64, wn = (wave & 1) * 32;

  f32x4 acc[4][2];
  #pragma unroll
  for (int mi = 0; mi < 4; mi++)
    #pragma unroll
    for (int ni = 0; ni < 2; ni++)
      #pragma unroll
      for (int r = 0; r < 4; r++) acc[mi][ni][r] = 0.f;

  for (int kt = 0; kt < 1024; kt += 64) {
    #pragma unroll
    for (int i = 0; i < 4; ++i) {
      int c = i * 256 + tid;
      int row = c >> 3, cg = c & 7;
      async16(A + (size_t)(m0 + row) * 1024 + kt + ((cg ^ (row & 7)) << 3),
              (char*)sA + i * 4096 + wave * 1024);
    }
    #pragma unroll
    for (int i = 0; i < 2; ++i) {
      int c = i * 256 + tid;
      int row = c >> 3, cg = c & 7;
      async16(W + (size_t)(n0 + row) * 1024 + kt + ((cg ^ (row & 7)) << 3),
              (char*)sB + i * 4096 + wave * 1024);
    }
    __syncthreads();
    #pragma unroll
    for (int kk = 0; kk < 2; ++kk) {
      bf16x8 af[4], bw[2];
      #pragma unroll
      for (int mi = 0; mi < 4; mi++) {
        int row = wm + mi * 16 + l16;
        af[mi] = *(const bf16x8*)&sA[row * 64 + (((quad + kk * 4) ^ (row & 7)) << 3)];
      }
      #pragma unroll
      for (int ni = 0; ni < 2; ni++) {
        int row = wn + ni * 16 + l16;
        bw[ni] = *(const bf16x8*)&sB[row * 64 + (((quad + kk * 4) ^ (row & 7)) << 3)];
      }
      #pragma unroll
      for (int mi = 0; mi < 4; mi++)
        #pragma unroll
        for (int ni = 0; ni < 2; ni++)
          acc[mi][ni] = __builtin_amdgcn_mfma_f32_16x16x32_bf16(bw[ni], af[mi], acc[mi][ni], 0, 0, 0);
    }
    __syncthreads();
  }
  #pragma unroll
  for (int mi = 0; mi < 4; mi++) {
    int m = m0 + wm + mi * 16 + l16;
    #pragma unroll
    for (int ni = 0; ni < 2; ni++) {
      int nb = n0 + wn + ni * 16 + quad * 4;
      f32x4 b4 = *(const f32x4*)&bias[nb];
      f32x4 r4 = *(const f32x4*)&resid[(size_t)m * 1024 + nb];
      f32x4 o;
      #pragma unroll
      for (int r = 0; r < 4; r++) o[r] = acc[mi][ni][r] + b4[r] + r4[r];
      *(f32x4*)&out[(size_t)m * 1024 + nb] = o;
    }
  }
}

// ---------------- flash attention: 32x32x16, register-P, per-kb fused ----------------
// Qp (pre-scaled), Kp: [B,S,E] bf16. Vt: [B,H,64,2048] bf16 with pi16-permuted keys.
// Block: 128 q (4 waves x 32), single-buffered K/V (32KB) -> 3 blocks/CU staggered.
// Per kb (32 keys): QK mfma -> exp2/pack (= PV B-frag via pi identity, HW-verified R7)
//   -> PV mfma immediately. sacc live = 16 regs (VGPR ~130 vs R7's 232).
// l via ones-MFMA: lacc = mfma(1, pfrag, lacc); all C rows = sum_k P[k][q] (both
//   half-lanes included) -> no VALU adds, no final shuffle.
__global__ __launch_bounds__(256, 3)
void attn_fused(const bf16* __restrict__ Qp, const bf16* __restrict__ Kp,
                const bf16* __restrict__ Vt, const unsigned char* __restrict__ mask,
                bf16* __restrict__ AO)
{
  __shared__ __align__(16) bf16 sK[128 * 64];   // 16KB [key][d] swizzled
  __shared__ __align__(16) bf16 sV[64 * 128];   // 16KB [d][key-pi] swizzled
  const int tid = threadIdx.x;
  const int wave = tid >> 6, lane = tid & 63, l31 = lane & 31, hl = lane >> 5;
  const int bh = blockIdx.x, qt = blockIdx.y;
  const int b = bh >> 4, h = bh & 15;
  const int q0 = qt * 128;
  const bf16* Kbase = Kp + (size_t)(b * 2048) * 1024 + h * 64;
  const bf16* Vbase = Vt + (size_t)bh * 64 * 2048;

  // Q B-frags from global: lane(q=l31,hl) holds Q[q][ks*16 + hl*8 .. +7]
  bf16x8 qf[4];
  {
    const bf16* Qrow = Qp + (size_t)(b * 2048 + q0 + wave * 32 + l31) * 1024 + h * 64;
    #pragma unroll
    for (int ks = 0; ks < 4; ks++)
      qf[ks] = *(const bf16x8*)(Qrow + ks * 16 + hl * 8);
  }

  // hoisted mask any-check (whole row, once): 2048 bytes / 64 lanes = 8 u32 each
  unsigned mor = 0;
  #pragma unroll
  for (int i = 0; i < 8; i++)
    mor |= ((const unsigned*)(mask + b * 2048))[lane + i * 64];
  const bool anymask = __any(mor != 0);

  auto stageKV = [&](int kt) {
    int k0 = kt * 128;
    #pragma unroll
    for (int i = 0; i < 4; i++) {
      int c = i * 256 + tid;
      int rk = c >> 3, cgk = c & 7;
      async16(Kbase + (size_t)(k0 + rk) * 1024 + ((cgk ^ (rk & 7)) << 3),
              (char*)sK + i * 4096 + wave * 1024);
      int d = c >> 4, cgv = c & 15;
      async16(Vbase + (size_t)d * 2048 + k0 + ((cgv ^ (d & 15)) << 3),
              (char*)sV + i * 4096 + wave * 1024);
    }
  };

  // ones A-frag for the l-accumulating MFMA
  bf16x8 ones;
  #pragma unroll
  for (int j = 0; j < 8; j++) ones[j] = (bf16)1.0f;

  f32x16 oacc[2], lacc;
  #pragma unroll
  for (int db = 0; db < 2; db++)
    #pragma unroll
    for (int r = 0; r < 16; r++) oacc[db][r] = 0.f;
  #pragma unroll
  for (int r = 0; r < 16; r++) lacc[r] = 0.f;

  stageKV(0);
  const float L2E = 1.44269504f;

  for (int kt = 0; kt < 16; ++kt) {
    __syncthreads();                       // staging visible
    #pragma unroll
    for (int kb = 0; kb < 4; kb++) {
      // S^T: C[key = kb*32 + (reg&3)+8*(reg>>2)+4*hl][q = l31]
      f32x16 sacc;
      #pragma unroll
      for (int r = 0; r < 16; r++) sacc[r] = 0.f;
      #pragma unroll
      for (int ks = 0; ks < 4; ks++) {
        bf16x8 ak = *(const bf16x8*)&sK[(kb * 32 + l31) * 64 + (((2 * ks + hl) ^ (l31 & 7)) << 3)];
        sacc = __builtin_amdgcn_mfma_f32_32x32x16_bf16(ak, qf[ks], sacc, 0, 0, 0);
      }
      if (anymask) {  // rare path: masked keys -> -1e30 -> exp2 -> 0
        int mbase = b * 2048 + kt * 128 + kb * 32;
        #pragma unroll
        for (int g2 = 0; g2 < 4; g2++) {
          unsigned m4 = *(const unsigned*)&mask[mbase + g2 * 8 + hl * 4];
          #pragma unroll
          for (int rr = 0; rr < 4; rr++)
            if ((m4 >> (8 * rr)) & 0xff) sacc[g2 * 4 + rr] = -1e30f;
        }
      }
      // exp2 + pack: pfrag[s][j] = exp2(sacc reg 8s+j) -- directly the PV B-frag
      bf16x8 pfrag[2];
      #pragma unroll
      for (int s = 0; s < 2; s++)
        #pragma unroll
        for (int j = 0; j < 8; j++)
          pfrag[s][j] = (bf16)__builtin_amdgcn_exp2f(sacc[8 * s + j] * L2E);
      // l += 1^T . P (all C rows equal sum_k P[k][q]); O^T += V' . P
      #pragma unroll
      for (int s = 0; s < 2; s++) {
        int g = kb * 2 + s;
        lacc = __builtin_amdgcn_mfma_f32_32x32x16_bf16(ones, pfrag[s], lacc, 0, 0, 0);
        #pragma unroll
        for (int db = 0; db < 2; db++) {
          bf16x8 av = *(const bf16x8*)&sV[(db * 32 + l31) * 128 + (((2 * g + hl) ^ (l31 & 15)) << 3)];
          oacc[db] = __builtin_amdgcn_mfma_f32_32x32x16_bf16(av, pfrag[s], oacc[db], 0, 0, 0);
        }
      }
    }
    __syncthreads();                       // reads done
    if (kt < 15) stageKV(kt + 1);
  }

  // finalize: l = lacc[0] (rows identical, both half-lanes summed by MFMA)
  float inv = 1.0f / lacc[0];
  int s = q0 + wave * 32 + l31;
  #pragma unroll
  for (int db = 0; db < 2; db++)
    #pragma unroll
    for (int g2 = 0; g2 < 4; g2++) {
      bf16x4 o;
      #pragma unroll
      for (int r = 0; r < 4; r++) o[r] = (bf16)(oacc[db][g2 * 4 + r] * inv);
      *(bf16x4*)&AO[(size_t)(b * 2048 + s) * 1024 + h * 64 + db * 32 + g2 * 8 + hl * 4] = o;
    }
}

extern "C" void kernel_launch(void* const* d_in, const int* in_sizes, int n_in,
                              void* d_out, int out_size, void* d_ws, size_t ws_size,
                              hipStream_t stream) {
  (void)in_sizes; (void)n_in; (void)out_size; (void)ws_size;
  const float* qf = (const float*)d_in[0];
  const float* kf = (const float*)d_in[1];
  const float* vf = (const float*)d_in[2];
  const unsigned char* mask = (const unsigned char*)d_in[3];
  const float* Wq = (const float*)d_in[4];
  const float* bq = (const float*)d_in[5];
  const float* Wk = (const float*)d_in[6];
  const float* bk = (const float*)d_in[7];
  const float* Wv = (const float*)d_in[8];
  const float* bv = (const float*)d_in[9];
  const float* Wo = (const float*)d_in[10];
  const float* bo = (const float*)d_in[11];

  bf16* p = (bf16*)d_ws;  // cast block must stay contiguous: Qb|Kb|Vb|Wqb|Wkb|Wvb|Wob
  bf16* Qb  = p; p += 4194304;
  bf16* Kb  = p; p += 4194304;
  bf16* Vb  = p; p += 4194304;
  bf16* Wqb = p; p += 1048576;
  bf16* Wkb = p; p += 1048576;
  bf16* Wvb = p; p += 1048576;
  bf16* Wob = p; p += 1048576;
  bf16* Qp  = p; p += 4194304;
  bf16* Kp  = p; p += 4194304;
  bf16* Vtp = p; p += 4194304;
  bf16* AO  = p; p += 4194304;

  cast_all<<<16384, 256, 0, stream>>>(qf, kf, vf, Wq, Wk, Wv, Wo, Qb);
  gemm_qkv<<<dim3(8, 32, 3), 256, 0, stream>>>(Qb, Kb, Vb, Wqb, Wkb, Wvb,
                                               bq, bk, bv, Qp, Kp, Vtp);
  attn_fused<<<dim3(32, 16), 256, 0, stream>>>(Qp, Kp, Vtp, mask, AO);
  gemm_o<<<dim3(16, 32), 256, 0, stream>>>(AO, Wob, bo, qf, (float*)d_out);
}